// Round 2
// baseline (19532.539 us; speedup 1.0000x reference)
//
#include <hip/hip_runtime.h>
#include <hip/hip_bf16.h>
#include <cstddef>
#include <cstdint>

// QuantizedThriftyNet on MI355X — round 1: fp32 baseline, workspace <= ~210.5 MiB.
// Round-0 post-mortem: 600s timeout, most likely an OOB write past d_ws
// (needed 258.3 MiB; 4x64MiB slabs alone = 256 MiB). Fix: in-place combine
// over the dying hist[1] slab => 3 full slabs + one 16 MiB bounce slab.
// Also fixed conv_fuse_kernel<8> weight-LDS fill (288 entries > 256 threads).
//
// Workspace layout:
//   3 slabs of 16*256*64*64 fp32 (64 MiB each)   = 192 MiB
//   1 slab of 16 MiB (only ever holds <=32x32 tensors)
//   wq (2.25 MiB) + small scratch

#define NB 16
#define NF 256
#define NIT 20

// ---------------- weight quantization: s = max|w|/127, wq = rint(w/s)*s ----
__global__ void wmax_part_kernel(const float* __restrict__ w, float* __restrict__ part, int n) {
  float m = 0.f;
  for (int i = blockIdx.x * blockDim.x + threadIdx.x; i < n; i += gridDim.x * blockDim.x)
    m = fmaxf(m, fabsf(w[i]));
  #pragma unroll
  for (int o = 32; o > 0; o >>= 1) m = fmaxf(m, __shfl_down(m, o));
  __shared__ float sm[4];
  int wid = threadIdx.x >> 6, lane = threadIdx.x & 63;
  if (lane == 0) sm[wid] = m;
  __syncthreads();
  if (threadIdx.x == 0) part[blockIdx.x] = fmaxf(fmaxf(sm[0], sm[1]), fmaxf(sm[2], sm[3]));
}

__global__ void wmax_final_kernel(const float* __restrict__ part, float* __restrict__ sout) {
  float m = part[threadIdx.x];  // exactly 256 partials, 256 threads
  #pragma unroll
  for (int o = 32; o > 0; o >>= 1) m = fmaxf(m, __shfl_down(m, o));
  __shared__ float sm[4];
  int wid = threadIdx.x >> 6, lane = threadIdx.x & 63;
  if (lane == 0) sm[wid] = m;
  __syncthreads();
  if (threadIdx.x == 0) sout[0] = fmaxf(fmaxf(sm[0], sm[1]), fmaxf(sm[2], sm[3])) / 127.f;
}

__global__ void quant_kernel(const float* __restrict__ w, const float* __restrict__ sptr,
                             float* __restrict__ wq, int n) {
  int i = blockIdx.x * blockDim.x + threadIdx.x;
  if (i >= n) return;
  float s = sptr[0];
  wq[i] = rintf(w[i] / s) * s;  // rintf = round-half-even, matches jnp.round
}

// ---------------- pad x (16,3,64,64) -> (16,256,64,64) with zero channels ---
__global__ void pad_kernel(const float* __restrict__ x, float* __restrict__ out) {
  int idx = blockIdx.x * 256 + threadIdx.x;  // 16*256*64*64 = 16,777,216
  int w = idx & 63, h = (idx >> 6) & 63, c = (idx >> 12) & 255, n = idx >> 20;
  float v = 0.f;
  if (c < 3) v = x[((n * 3 + c) << 12) + (h << 6) + w];
  out[idx] = v;
}

// ---------------- fused conv3x3 + relu + alpha-combine --------------------
// block: (S, 256/S) threads; each thread computes HT=4 output rows for one
// (n, co, :, w). LDS stages (HT+2) input rows + CO_T*9 weights per ci.
// NOTE: `pre` may alias h1 — each thread reads h1[idx] then writes pre[idx]
// at the same idx, and idx partitions the tensor across threads, so the
// in-place overwrite of the dying hist[1] slab is race-free. `in`==h3 (the
// halo-read tensor) is always a different slab than pre.
template <int S>
__global__ __launch_bounds__(256) void conv_fuse_kernel(
    const float* __restrict__ in, const float* __restrict__ wq,
    const float* __restrict__ alpha, int t,
    const float* __restrict__ h1, const float* __restrict__ h2,
    const float* __restrict__ h3, float* __restrict__ pre) {
  constexpr int CO_T = 256 / S;
  constexpr int HT = 4;
  constexpr int LW = S + 2;
  __shared__ float lds_in[(HT + 2) * LW];
  __shared__ float lds_w[CO_T * 9];
  const int tx = threadIdx.x;           // w
  const int ty = threadIdx.y;           // co within group
  const int tid = ty * S + tx;
  const int hgroups = S / HT;
  const int n = blockIdx.x / hgroups;
  const int h0 = (blockIdx.x % hgroups) * HT;
  const int co = blockIdx.y * CO_T + ty;

  float acc[HT];
  #pragma unroll
  for (int h = 0; h < HT; ++h) acc[h] = 0.f;

  for (int ci = 0; ci < 256; ++ci) {
    const float* src = in + ((size_t)(n * 256 + ci)) * S * S;
    for (int idx = tid; idx < (HT + 2) * LW; idx += 256) {
      int r = idx / LW, c = idx - r * LW;
      int hi = h0 + r - 1, wi = c - 1;
      float v = 0.f;
      if (hi >= 0 && hi < S && (unsigned)wi < (unsigned)S) v = src[hi * S + wi];
      lds_in[idx] = v;
    }
    for (int idx = tid; idx < CO_T * 9; idx += 256) {  // loop: CO_T*9 can exceed 256 (S=8)
      int o = idx / 9, k = idx - o * 9;
      lds_w[idx] = wq[((size_t)(blockIdx.y * CO_T + o) * 256 + ci) * 9 + k];
    }
    __syncthreads();
    float w[9];
    #pragma unroll
    for (int k = 0; k < 9; ++k) w[k] = lds_w[ty * 9 + k];
    float v[HT + 2][3];
    #pragma unroll
    for (int r = 0; r < HT + 2; ++r)
      #pragma unroll
      for (int k = 0; k < 3; ++k) v[r][k] = lds_in[r * LW + tx + k];
    #pragma unroll
    for (int h = 0; h < HT; ++h)
      acc[h] += w[0] * v[h][0] + w[1] * v[h][1] + w[2] * v[h][2]
              + w[3] * v[h + 1][0] + w[4] * v[h + 1][1] + w[5] * v[h + 1][2]
              + w[6] * v[h + 2][0] + w[7] * v[h + 2][1] + w[8] * v[h + 2][2];
    __syncthreads();
  }

  // epilogue: pre = a0*relu(conv) + a1*h1 + a2*h2 + a3*h3
  const float a0 = alpha[t * 5 + 0];
  const float a1 = alpha[t * 5 + 2];  // hist[1] -> alpha[t,2]
  const float a2 = alpha[t * 5 + 3];  // hist[2] -> alpha[t,3]
  const float a3 = alpha[t * 5 + 4];  // hist[3] -> alpha[t,4]
  #pragma unroll
  for (int h = 0; h < HT; ++h) {
    size_t idx = ((size_t)(n * 256 + co) * S + (h0 + h)) * S + tx;
    float p = a0 * fmaxf(acc[h], 0.f);
    if (h1) p += a1 * h1[idx];
    if (h2) p += a2 * h2[idx];
    p += a3 * h3[idx];
    pre[idx] = p;
  }
}

// ---------------- per-channel batch stats -> scale/shift -------------------
__global__ void stats_kernel(const float* __restrict__ pre, int SS,
                             const float* __restrict__ gamma, const float* __restrict__ beta,
                             int t, float* __restrict__ scale, float* __restrict__ shift) {
  int c = blockIdx.x;
  float s = 0.f, s2 = 0.f;
  for (int n = 0; n < NB; ++n) {
    const float* p = pre + ((size_t)(n * 256 + c)) * SS;
    for (int i = threadIdx.x; i < SS; i += blockDim.x) {
      float v = p[i];
      s += v;
      s2 += v * v;
    }
  }
  #pragma unroll
  for (int o = 32; o > 0; o >>= 1) {
    s += __shfl_down(s, o);
    s2 += __shfl_down(s2, o);
  }
  __shared__ float as[4], as2[4];
  int wid = threadIdx.x >> 6, lane = threadIdx.x & 63;
  if (lane == 0) { as[wid] = s; as2[wid] = s2; }
  __syncthreads();
  if (threadIdx.x == 0) {
    s = as[0] + as[1] + as[2] + as[3];
    s2 = as2[0] + as2[1] + as2[2] + as2[3];
    float M = (float)(NB * SS);
    float mean = s / M;
    float var = s2 / M - mean * mean;  // biased (ddof=0), matches jnp.var
    float sc = gamma[t * 256 + c] * rsqrtf(var + 1e-5f);
    scale[c] = sc;
    shift[c] = beta[t * 256 + c] - mean * sc;
  }
}

// ---------------- BN apply (in place) --------------------------------------
__global__ void apply_kernel(float* __restrict__ a, const float* __restrict__ scale,
                             const float* __restrict__ shift, int SS) {
  int n = blockIdx.x, c = blockIdx.y;
  float sc = scale[c], sh = shift[c];
  float* p = a + ((size_t)(n * 256 + c)) * SS;
  for (int i = threadIdx.x; i < SS; i += blockDim.x) p[i] = p[i] * sc + sh;
}

// ---------------- 2x2 max pool ---------------------------------------------
__global__ void pool_kernel(const float* __restrict__ in, float* __restrict__ out,
                            int So, int total) {
  int idx = blockIdx.x * 256 + threadIdx.x;
  if (idx >= total) return;
  int w = idx % So;
  int t1 = idx / So;
  int h = t1 % So;
  int nc = t1 / So;
  int Si = So * 2;
  const float* p = in + ((size_t)nc * Si + 2 * h) * Si + 2 * w;
  out[idx] = fmaxf(fmaxf(p[0], p[1]), fmaxf(p[Si], p[Si + 1]));
}

// ---------------- final spatial max (S=4 -> 16 elems contiguous) -----------
__global__ void amax_kernel(const float* __restrict__ a, float* __restrict__ vec) {
  int i = blockIdx.x * blockDim.x + threadIdx.x;  // 0..4095 = n*256+c
  if (i >= NB * 256) return;
  const float* p = a + (size_t)i * 16;
  float m = p[0];
  #pragma unroll
  for (int k = 1; k < 16; ++k) m = fmaxf(m, p[k]);
  vec[i] = m;
}

// ---------------- linear head ----------------------------------------------
__global__ void linear_kernel(const float* __restrict__ vec, const float* __restrict__ W,
                              const float* __restrict__ b, float* __restrict__ out) {
  int n = blockIdx.x, j = threadIdx.x;
  if (j >= 100) return;
  float s = b[j];
  const float* v = vec + n * 256;
  const float* w = W + j * 256;
  for (int c = 0; c < 256; ++c) s += v[c] * w[c];
  out[n * 100 + j] = s;
}

// ---------------------------------------------------------------------------
static inline void launch_conv(int S, const float* in, const float* wq, const float* alpha,
                               int t, const float* h1, const float* h2, const float* h3,
                               float* pre, hipStream_t stream) {
  dim3 grid(16 * (S / 4), S);        // S/4 h-groups per n; gridY = #co groups = S
  dim3 block(S, 256 / S);
  switch (S) {
    case 64: hipLaunchKernelGGL((conv_fuse_kernel<64>), grid, block, 0, stream, in, wq, alpha, t, h1, h2, h3, pre); break;
    case 32: hipLaunchKernelGGL((conv_fuse_kernel<32>), grid, block, 0, stream, in, wq, alpha, t, h1, h2, h3, pre); break;
    case 16: hipLaunchKernelGGL((conv_fuse_kernel<16>), grid, block, 0, stream, in, wq, alpha, t, h1, h2, h3, pre); break;
    case 8:  hipLaunchKernelGGL((conv_fuse_kernel<8>),  grid, block, 0, stream, in, wq, alpha, t, h1, h2, h3, pre); break;
  }
}

extern "C" void kernel_launch(void* const* d_in, const int* in_sizes, int n_in,
                              void* d_out, int out_size, void* d_ws, size_t ws_size,
                              hipStream_t stream) {
  const float* x        = (const float*)d_in[0];  // (16,3,64,64)
  const float* conv_w   = (const float*)d_in[1];  // (256,256,3,3)
  const float* alpha    = (const float*)d_in[2];  // (20,5)
  const float* bn_gamma = (const float*)d_in[3];  // (20,256)
  const float* bn_beta  = (const float*)d_in[4];  // (20,256)
  const float* out_w    = (const float*)d_in[5];  // (100,256)
  const float* out_b    = (const float*)d_in[6];  // (100,)
  float* out = (float*)d_out;                     // (16,100)

  char* ws = (char*)d_ws;
  size_t off = 0;
  auto alloc = [&](size_t bytes) -> float* {
    float* p = (float*)(ws + off);
    off = (off + bytes + 255) & ~(size_t)255;
    return p;
  };
  const size_t BUF_BYTES   = (size_t)NB * 256 * 64 * 64 * 4;  // 64 MiB
  const size_t SMALL_BYTES = BUF_BYTES / 4;                   // 16 MiB (<=32x32 tensors)
  float* bufs[4];
  for (int i = 0; i < 3; ++i) bufs[i] = alloc(BUF_BYTES);
  bufs[3] = alloc(SMALL_BYTES);   // slab 3: only used for S<=32 tensors
  float* wq    = alloc((size_t)256 * 256 * 9 * 4);
  float* wpart = alloc(256 * 4);
  float* sq    = alloc(256);
  float* scale = alloc(256 * 4);
  float* shift = alloc(256 * 4);
  float* vec   = alloc((size_t)NB * 256 * 4);
  (void)ws_size;  // total ~210.5 MiB

  const int NW = 256 * 256 * 9;  // 589824 weight elements

  // 1) quantize weights
  hipLaunchKernelGGL(wmax_part_kernel, dim3(256), dim3(256), 0, stream, conv_w, wpart, NW);
  hipLaunchKernelGGL(wmax_final_kernel, dim3(1), dim3(256), 0, stream, wpart, sq);
  hipLaunchKernelGGL(quant_kernel, dim3((NW + 255) / 256), dim3(256), 0, stream, conv_w, sq, wq, NW);

  // 2) pad input into slab 0
  hipLaunchKernelGGL(pad_kernel, dim3((NB * 256 * 64 * 64) / 256), dim3(256), 0, stream, x, bufs[0]);

  // 3) 20 iterations
  int i1 = -1, i2 = -1, i3 = 0;  // hist[1],hist[2],hist[3] slab indices
  int S = 64;
  for (int t = 0; t < NIT; ++t) {
    // choose destination slab: overwrite dying hist[1] in place when it exists;
    // otherwise first free slab (skip the 16 MiB slab 3 while tensors are 64 MiB).
    int idst;
    if (i1 >= 0) {
      idst = i1;
    } else {
      idst = -1;
      int limit = (S == 64) ? 3 : 4;
      for (int b = 0; b < limit; ++b)
        if (b != i1 && b != i2 && b != i3) { idst = b; break; }
    }
    const float* h1 = (i1 >= 0) ? bufs[i1] : nullptr;
    const float* h2 = (i2 >= 0) ? bufs[i2] : nullptr;
    const float* h3 = bufs[i3];
    float* pre = bufs[idst];

    launch_conv(S, h3, wq, alpha, t, h1, h2, h3, pre, stream);
    hipLaunchKernelGGL(stats_kernel, dim3(256), dim3(256), 0, stream,
                       pre, S * S, bn_gamma, bn_beta, t, scale, shift);
    hipLaunchKernelGGL(apply_kernel, dim3(NB, 256), dim3(256), 0, stream,
                       pre, scale, shift, S * S);

    // hist shift: [None, h2, h3, a]
    i1 = i2; i2 = i3; i3 = idst;

    if (t % 5 == 4) {
      int So = S / 2;
      int total = NB * 256 * So * So;
      int fr = -1;
      for (int b = 0; b < 4; ++b)
        if (b != i1 && b != i2 && b != i3) { fr = b; break; }
      // cascade: h1 -> free, h2 -> h1's old slab, h3 -> h2's old slab.
      // Pooled size <= 16 MiB, so slab 3 is a legal destination here.
      hipLaunchKernelGGL(pool_kernel, dim3((total + 255) / 256), dim3(256), 0, stream,
                         bufs[i1], bufs[fr], So, total);
      { int old = i1; i1 = fr; fr = old; }
      hipLaunchKernelGGL(pool_kernel, dim3((total + 255) / 256), dim3(256), 0, stream,
                         bufs[i2], bufs[fr], So, total);
      { int old = i2; i2 = fr; fr = old; }
      hipLaunchKernelGGL(pool_kernel, dim3((total + 255) / 256), dim3(256), 0, stream,
                         bufs[i3], bufs[fr], So, total);
      { int old = i3; i3 = fr; fr = old; }
      S = So;
    }
  }

  // 4) final spatial max (S=4) + linear head
  hipLaunchKernelGGL(amax_kernel, dim3(16), dim3(256), 0, stream, bufs[i3], vec);
  hipLaunchKernelGGL(linear_kernel, dim3(NB), dim3(128), 0, stream, vec, out_w, out_b, out);
}

// Round 3
// 3446.999 us; speedup vs baseline: 5.6665x; 5.6665x over previous
//
#include <hip/hip_runtime.h>
#include <hip/hip_fp16.h>
#include <cstddef>
#include <cstdint>

// QuantizedThriftyNet on MI355X — round 2: f16 MFMA implicit-GEMM conv, NHWC.
// Round-1 counters: conv fp32 direct = VALU-bound (MfmaUtil 0, VALUBusy 84%,
// 24 GFLOP/ms). Moving conv to the matrix pipe via 16x16x32 f16 MFMA.
//   activations: NHWC _Float16 slabs (32 MiB full-res)
//   weights:     quantized, f16, layout [tap][co][ci] (1.18 MB, L2-resident)
//   conv block:  512 thr (8 waves, 4Mx2N), out = 256 co x 64 pixels,
//                K = 8 ci-chunks x 9 taps; X tile in LDS, XOR-swizzled 16B chunks
//   epilogue:    relu + alpha-combine fused, in-place over dying hist[1]
// BN stats: two-stage deterministic partials (NHWC-coalesced).

#define NB 16
#define NIT 20

typedef _Float16 half8 __attribute__((ext_vector_type(8)));
typedef _Float16 half4v __attribute__((ext_vector_type(4)));
typedef float floatx4 __attribute__((ext_vector_type(4)));

// ---------------- weight max -> scale ---------------------------------------
__global__ void wmax_part_kernel(const float* __restrict__ w, float* __restrict__ part, int n) {
  float m = 0.f;
  for (int i = blockIdx.x * blockDim.x + threadIdx.x; i < n; i += gridDim.x * blockDim.x)
    m = fmaxf(m, fabsf(w[i]));
  #pragma unroll
  for (int o = 32; o > 0; o >>= 1) m = fmaxf(m, __shfl_down(m, o));
  __shared__ float sm[4];
  int wid = threadIdx.x >> 6, lane = threadIdx.x & 63;
  if (lane == 0) sm[wid] = m;
  __syncthreads();
  if (threadIdx.x == 0) part[blockIdx.x] = fmaxf(fmaxf(sm[0], sm[1]), fmaxf(sm[2], sm[3]));
}

__global__ void wmax_final_kernel(const float* __restrict__ part, float* __restrict__ sout) {
  float m = part[threadIdx.x];  // 256 partials
  #pragma unroll
  for (int o = 32; o > 0; o >>= 1) m = fmaxf(m, __shfl_down(m, o));
  __shared__ float sm[4];
  int wid = threadIdx.x >> 6, lane = threadIdx.x & 63;
  if (lane == 0) sm[wid] = m;
  __syncthreads();
  if (threadIdx.x == 0) sout[0] = fmaxf(fmaxf(sm[0], sm[1]), fmaxf(sm[2], sm[3])) / 127.f;
}

// quantize + transpose to [tap][co][ci], f16
__global__ void quant_kernel(const float* __restrict__ w, const float* __restrict__ sptr,
                             _Float16* __restrict__ wqt, int nw) {
  int i = blockIdx.x * 256 + threadIdx.x;
  if (i >= nw) return;
  float s = sptr[0];
  float q = rintf(w[i] / s) * s;        // round-half-even, matches jnp.round
  int k = i % 9;
  int ci = (i / 9) & 255;
  int co = i / 2304;
  wqt[((size_t)(k * 256 + co)) * 256 + ci] = (_Float16)q;
}

// ---------------- pad x (16,3,64,64) fp32 NCHW -> (16,4096,256) f16 NHWC ----
__global__ void pad_kernel(const float* __restrict__ x, _Float16* __restrict__ out) {
  int idx = blockIdx.x * 256 + threadIdx.x;   // 16*4096*256
  int c = idx & 255;
  int pos = idx >> 8;
  int hw = pos & 4095;
  int n = pos >> 12;
  float v = 0.f;
  if (c < 3) v = x[(n * 3 + c) * 4096 + hw];
  out[idx] = (_Float16)v;
}

// ---------------- MFMA conv3x3 + relu + alpha-combine (NHWC f16) ------------
// Block: 512 threads (8 waves, wm=wid>>1 in 0..3 over co, wn=wid&1 over pos).
// Output tile: 256 co x 64 pixels. K-loop: ci chunks of 32, taps inner.
// LDS X tile: (R+2) x (S+2) halo pixels x 32 ci, 16B chunks XOR-swizzled.
template <int S>
__global__ __launch_bounds__(512) void conv_mfma_kernel(
    const _Float16* __restrict__ in, const _Float16* __restrict__ wqt,
    const float* __restrict__ alpha, int t,
    const _Float16* __restrict__ h1, const _Float16* __restrict__ h2,
    const _Float16* __restrict__ h3, _Float16* __restrict__ pre) {
  constexpr int R = 64 / S;          // output rows per block (S=64 -> 1)
  constexpr int LW = S + 2;
  constexpr int PIX = (R + 2) * LW;  // halo pixels per tile
  __shared__ half8 xl[PIX * 4];      // [pix][4 swizzled 16B ci-chunks]

  const int tid = threadIdx.x;
  const int lane = tid & 63;
  const int wid = tid >> 6;
  const int wm = wid >> 1;           // co block (0..3) -> rows wm*64..+63
  const int wn = wid & 1;            // pos block (0..1) -> cols wn*32..+31
  const int l16 = lane & 15;
  const int kg = lane >> 4;          // 0..3 (8-ci group)

  const int bpi = (S * S) / 64;      // blocks per image
  const int n = blockIdx.x / bpi;
  const int rg = blockIdx.x % bpi;
  const int hb = rg * R;
  const int pix_base = blockIdx.x * 64;

  // per-lane B-fragment LDS pixel bases (2 N-frags)
  int lpb[2];
  #pragma unroll
  for (int g = 0; g < 2; ++g) {
    int pl = wn * 32 + g * 16 + l16;   // 0..63 local pos
    int r = pl / S, w = pl % S;
    lpb[g] = (r + 1) * LW + (w + 1);
  }

  floatx4 acc[4][2];
  #pragma unroll
  for (int f = 0; f < 4; ++f)
    #pragma unroll
    for (int g = 0; g < 2; ++g)
      acc[f][g] = (floatx4){0.f, 0.f, 0.f, 0.f};

  for (int ci0 = 0; ci0 < 256; ci0 += 32) {
    // ---- stage X tile (32 ci) into LDS, swizzled, zero halo ----
    for (int c = tid; c < PIX * 4; c += 512) {
      int pix = c >> 2, cig = c & 3;
      int hp = pix / LW, wp = pix % LW;
      int h = hb + hp - 1, w = wp - 1;
      half8 v = {};
      if ((unsigned)h < (unsigned)S && (unsigned)w < (unsigned)S)
        v = *(const half8*)(in + ((size_t)(n * S * S + h * S + w) * 256 + ci0 + cig * 8));
      xl[pix * 4 + (cig ^ ((pix >> 1) & 3))] = v;
    }
    __syncthreads();

    #pragma unroll
    for (int dh = -1; dh <= 1; ++dh) {
      #pragma unroll
      for (int dw = -1; dw <= 1; ++dw) {
        const int tap = (dh + 1) * 3 + (dw + 1);
        half8 af[4];
        #pragma unroll
        for (int f = 0; f < 4; ++f) {
          int co = wm * 64 + f * 16 + l16;
          af[f] = *(const half8*)(wqt + ((size_t)(tap * 256 + co)) * 256 + ci0 + kg * 8);
        }
        half8 bf[2];
        #pragma unroll
        for (int g = 0; g < 2; ++g) {
          int lp = lpb[g] + dh * LW + dw;
          bf[g] = xl[lp * 4 + (kg ^ ((lp >> 1) & 3))];
        }
        #pragma unroll
        for (int f = 0; f < 4; ++f)
          #pragma unroll
          for (int g = 0; g < 2; ++g)
            acc[f][g] = __builtin_amdgcn_mfma_f32_16x16x32_f16(af[f], bf[g], acc[f][g], 0, 0, 0);
      }
    }
    __syncthreads();
  }

  // ---- epilogue: pre = a0*relu(conv) + a1*h1 + a2*h2 + a3*h3 ----
  // D frag: col(pos) = lane&15, row(co) = (lane>>4)*4 + reg  (4 consecutive co)
  const float a0 = alpha[t * 5 + 0];
  const float a1 = alpha[t * 5 + 2];
  const float a2 = alpha[t * 5 + 3];
  const float a3 = alpha[t * 5 + 4];
  #pragma unroll
  for (int f = 0; f < 4; ++f) {
    int co = wm * 64 + f * 16 + kg * 4;
    #pragma unroll
    for (int g = 0; g < 2; ++g) {
      int pg = pix_base + wn * 32 + g * 16 + l16;
      size_t idx = (size_t)pg * 256 + co;
      half4v v3 = *(const half4v*)(h3 + idx);
      half4v v1 = {}, v2 = {};
      if (h1) v1 = *(const half4v*)(h1 + idx);
      if (h2) v2 = *(const half4v*)(h2 + idx);
      half4v o;
      #pragma unroll
      for (int r = 0; r < 4; ++r) {
        float p = a0 * fmaxf(acc[f][g][r], 0.f) + a3 * (float)v3[r];
        if (h1) p += a1 * (float)v1[r];
        if (h2) p += a2 * (float)v2[r];
        o[r] = (_Float16)p;
      }
      *(half4v*)(pre + idx) = o;   // pre may alias h1: same-thread RaW, safe
    }
  }
}

// ---------------- BN stats: two-stage, deterministic ------------------------
__global__ void stats_part_kernel(const _Float16* __restrict__ x, int npix,
                                  float* __restrict__ psum, float* __restrict__ psum2) {
  int c = threadIdx.x;   // channel
  int b = blockIdx.x;    // 256 blocks
  float s = 0.f, s2 = 0.f;
  for (int p = b; p < npix; p += 256) {
    float v = (float)x[(size_t)p * 256 + c];
    s += v;
    s2 += v * v;
  }
  psum[b * 256 + c] = s;
  psum2[b * 256 + c] = s2;
}

__global__ void stats_final_kernel(const float* __restrict__ psum, const float* __restrict__ psum2,
                                   const float* __restrict__ gamma, const float* __restrict__ beta,
                                   int t, float M, float* __restrict__ scale,
                                   float* __restrict__ shift) {
  int c = threadIdx.x;
  float s = 0.f, s2 = 0.f;
  for (int b = 0; b < 256; ++b) {
    s += psum[b * 256 + c];
    s2 += psum2[b * 256 + c];
  }
  float mean = s / M;
  float var = s2 / M - mean * mean;  // biased, matches jnp.var
  float sc = gamma[t * 256 + c] * rsqrtf(var + 1e-5f);
  scale[c] = sc;
  shift[c] = beta[t * 256 + c] - mean * sc;
}

// ---------------- BN apply (in place, x8 vectorized) ------------------------
__global__ void apply_kernel(_Float16* __restrict__ x, const float* __restrict__ scale,
                             const float* __restrict__ shift, int n8) {
  int i = blockIdx.x * 256 + threadIdx.x;
  if (i >= n8) return;
  half8 v = *(half8*)(x + (size_t)i * 8);
  int c0 = (i * 8) & 255;
  half8 o;
  #pragma unroll
  for (int j = 0; j < 8; ++j) o[j] = (_Float16)((float)v[j] * scale[c0 + j] + shift[c0 + j]);
  *(half8*)(x + (size_t)i * 8) = o;
}

// ---------------- 2x2 max pool (NHWC, x8 channels/thread) -------------------
__global__ void pool_kernel(const _Float16* __restrict__ in, _Float16* __restrict__ out,
                            int So, int total8) {
  int i = blockIdx.x * 256 + threadIdx.x;
  if (i >= total8) return;
  int c0 = (i & 31) * 8;
  int pix = i >> 5;
  int wo = pix % So;
  int t1 = pix / So;
  int ho = t1 % So;
  int n = t1 / So;
  int Si = So * 2;
  size_t b00 = ((size_t)(n * Si * Si) + (2 * ho) * Si + 2 * wo) * 256 + c0;
  half8 v00 = *(const half8*)(in + b00);
  half8 v01 = *(const half8*)(in + b00 + 256);
  half8 v10 = *(const half8*)(in + b00 + (size_t)Si * 256);
  half8 v11 = *(const half8*)(in + b00 + (size_t)Si * 256 + 256);
  half8 o;
  #pragma unroll
  for (int j = 0; j < 8; ++j) {
    float m = fmaxf(fmaxf((float)v00[j], (float)v01[j]), fmaxf((float)v10[j], (float)v11[j]));
    o[j] = (_Float16)m;
  }
  *(half8*)(out + (size_t)pix * 256 + c0) = o;
}

// ---------------- final spatial max (S=4) -> f32 vec ------------------------
__global__ void amax_kernel(const _Float16* __restrict__ x, float* __restrict__ vec) {
  int i = blockIdx.x * blockDim.x + threadIdx.x;  // n*256+c
  if (i >= NB * 256) return;
  int n = i >> 8, c = i & 255;
  float m = -1e30f;
  for (int p = 0; p < 16; ++p)
    m = fmaxf(m, (float)x[((size_t)(n * 16 + p)) * 256 + c]);
  vec[i] = m;
}

// ---------------- linear head ------------------------------------------------
__global__ void linear_kernel(const float* __restrict__ vec, const float* __restrict__ W,
                              const float* __restrict__ b, float* __restrict__ out) {
  int n = blockIdx.x, j = threadIdx.x;
  if (j >= 100) return;
  float s = b[j];
  const float* v = vec + n * 256;
  const float* w = W + j * 256;
  for (int c = 0; c < 256; ++c) s += v[c] * w[c];
  out[n * 100 + j] = s;
}

// ---------------------------------------------------------------------------
static inline void launch_conv(int S, const _Float16* in, const _Float16* wqt,
                               const float* alpha, int t, const _Float16* h1,
                               const _Float16* h2, const _Float16* h3, _Float16* pre,
                               hipStream_t stream) {
  int blocks = (NB * S * S) / 64;
  dim3 grid(blocks), block(512);
  switch (S) {
    case 64: hipLaunchKernelGGL((conv_mfma_kernel<64>), grid, block, 0, stream, in, wqt, alpha, t, h1, h2, h3, pre); break;
    case 32: hipLaunchKernelGGL((conv_mfma_kernel<32>), grid, block, 0, stream, in, wqt, alpha, t, h1, h2, h3, pre); break;
    case 16: hipLaunchKernelGGL((conv_mfma_kernel<16>), grid, block, 0, stream, in, wqt, alpha, t, h1, h2, h3, pre); break;
    case 8:  hipLaunchKernelGGL((conv_mfma_kernel<8>),  grid, block, 0, stream, in, wqt, alpha, t, h1, h2, h3, pre); break;
  }
}

extern "C" void kernel_launch(void* const* d_in, const int* in_sizes, int n_in,
                              void* d_out, int out_size, void* d_ws, size_t ws_size,
                              hipStream_t stream) {
  const float* x        = (const float*)d_in[0];  // (16,3,64,64)
  const float* conv_w   = (const float*)d_in[1];  // (256,256,3,3)
  const float* alpha    = (const float*)d_in[2];  // (20,5)
  const float* bn_gamma = (const float*)d_in[3];  // (20,256)
  const float* bn_beta  = (const float*)d_in[4];  // (20,256)
  const float* out_w    = (const float*)d_in[5];  // (100,256)
  const float* out_b    = (const float*)d_in[6];  // (100,)
  float* out = (float*)d_out;                     // (16,100)

  char* ws = (char*)d_ws;
  size_t off = 0;
  auto alloc = [&](size_t bytes) -> void* {
    void* p = (void*)(ws + off);
    off = (off + bytes + 255) & ~(size_t)255;
    return p;
  };
  const size_t FULL_BYTES  = (size_t)NB * 4096 * 256 * 2;  // 32 MiB f16 NHWC
  const size_t SMALL_BYTES = FULL_BYTES / 4;               // 8 MiB (<=32x32)
  _Float16* bufs[4];
  for (int i = 0; i < 3; ++i) bufs[i] = (_Float16*)alloc(FULL_BYTES);
  bufs[3] = (_Float16*)alloc(SMALL_BYTES);
  _Float16* wqt  = (_Float16*)alloc((size_t)9 * 256 * 256 * 2);
  float* wpart = (float*)alloc(256 * 4);
  float* sq    = (float*)alloc(256);
  float* psum  = (float*)alloc(256 * 256 * 4);
  float* psum2 = (float*)alloc(256 * 256 * 4);
  float* scale = (float*)alloc(256 * 4);
  float* shift = (float*)alloc(256 * 4);
  float* vec   = (float*)alloc((size_t)NB * 256 * 4);
  (void)ws_size;  // ~107 MiB total

  const int NW = 256 * 256 * 9;

  // 1) quantize + transpose weights -> f16 [tap][co][ci]
  hipLaunchKernelGGL(wmax_part_kernel, dim3(256), dim3(256), 0, stream, conv_w, wpart, NW);
  hipLaunchKernelGGL(wmax_final_kernel, dim3(1), dim3(256), 0, stream, wpart, sq);
  hipLaunchKernelGGL(quant_kernel, dim3((NW + 255) / 256), dim3(256), 0, stream, conv_w, sq, wqt, NW);

  // 2) pad input -> NHWC f16 slab 0
  hipLaunchKernelGGL(pad_kernel, dim3((NB * 4096 * 256) / 256), dim3(256), 0, stream, x, bufs[0]);

  // 3) 20 iterations
  int i1 = -1, i2 = -1, i3 = 0;
  int S = 64;
  for (int t = 0; t < NIT; ++t) {
    int idst;
    if (i1 >= 0) {
      idst = i1;  // overwrite dying hist[1] in place
    } else {
      idst = -1;
      int limit = (S == 64) ? 3 : 4;
      for (int b = 0; b < limit; ++b)
        if (b != i1 && b != i2 && b != i3) { idst = b; break; }
    }
    const _Float16* h1 = (i1 >= 0) ? bufs[i1] : nullptr;
    const _Float16* h2 = (i2 >= 0) ? bufs[i2] : nullptr;
    const _Float16* h3 = bufs[i3];
    _Float16* pre = bufs[idst];

    launch_conv(S, h3, wqt, alpha, t, h1, h2, h3, pre, stream);

    int npix = NB * S * S;
    hipLaunchKernelGGL(stats_part_kernel, dim3(256), dim3(256), 0, stream, pre, npix, psum, psum2);
    hipLaunchKernelGGL(stats_final_kernel, dim3(1), dim3(256), 0, stream,
                       psum, psum2, bn_gamma, bn_beta, t, (float)npix, scale, shift);
    int n8 = npix * 32;  // npix*256/8
    hipLaunchKernelGGL(apply_kernel, dim3((n8 + 255) / 256), dim3(256), 0, stream,
                       pre, scale, shift, n8);

    i1 = i2; i2 = i3; i3 = idst;

    if (t % 5 == 4) {
      int So = S / 2;
      int total8 = NB * So * So * 32;
      int fr = -1;
      for (int b = 0; b < 4; ++b)
        if (b != i1 && b != i2 && b != i3) { fr = b; break; }
      hipLaunchKernelGGL(pool_kernel, dim3((total8 + 255) / 256), dim3(256), 0, stream,
                         bufs[i1], bufs[fr], So, total8);
      { int old = i1; i1 = fr; fr = old; }
      hipLaunchKernelGGL(pool_kernel, dim3((total8 + 255) / 256), dim3(256), 0, stream,
                         bufs[i2], bufs[fr], So, total8);
      { int old = i2; i2 = fr; fr = old; }
      hipLaunchKernelGGL(pool_kernel, dim3((total8 + 255) / 256), dim3(256), 0, stream,
                         bufs[i3], bufs[fr], So, total8);
      { int old = i3; i3 = fr; fr = old; }
      S = So;
    }
  }

  // 4) final spatial max + linear head
  hipLaunchKernelGGL(amax_kernel, dim3(16), dim3(256), 0, stream, bufs[i3], vec);
  hipLaunchKernelGGL(linear_kernel, dim3(NB), dim3(128), 0, stream, vec, out_w, out_b, out);
}

// Round 4
// 1665.366 us; speedup vs baseline: 11.7287x; 2.0698x over previous
//
#include <hip/hip_runtime.h>
#include <hip/hip_fp16.h>
#include <cstddef>
#include <cstdint>

// QuantizedThriftyNet on MI355X — round 3: deep-tiled MFMA conv.
// Round-2 counters: conv MfmaUtil 10%, VALUBusy 9%, HBM 7% => latency-bound,
// with 4x-redundant weight fetches from L2. This round:
//   * 256-pix x 64-co tiles, 8 waves (2 co x 4 pix), K = 8 chunks x 32 ci
//   * double-buffered LDS for X tile AND weight fragments (~126 KB, 1 blk/CU)
//   * staging via global_load_lds (width 16), linear LDS dest, pre-swizzled
//     per-lane global source; halo lanes read a zeroed 64B page
//   * weights repacked to coalesced 1KB MFMA fragments at quant time
//   * BN stats fused into conv epilogue (deterministic partials per block)

#define NB 16
#define NIT 20

typedef _Float16 half8 __attribute__((ext_vector_type(8)));
typedef _Float16 half4v __attribute__((ext_vector_type(4)));
typedef float floatx4 __attribute__((ext_vector_type(4)));

__device__ __forceinline__ void gl_lds16(const void* g, void* l) {
  __builtin_amdgcn_global_load_lds(
      (const __attribute__((address_space(1))) unsigned int*)g,
      (__attribute__((address_space(3))) unsigned int*)l, 16, 0, 0);
}

// ---------------- weight max -> scale ---------------------------------------
__global__ void wmax_part_kernel(const float* __restrict__ w, float* __restrict__ part, int n) {
  float m = 0.f;
  for (int i = blockIdx.x * blockDim.x + threadIdx.x; i < n; i += gridDim.x * blockDim.x)
    m = fmaxf(m, fabsf(w[i]));
  #pragma unroll
  for (int o = 32; o > 0; o >>= 1) m = fmaxf(m, __shfl_down(m, o));
  __shared__ float sm[4];
  int wid = threadIdx.x >> 6, lane = threadIdx.x & 63;
  if (lane == 0) sm[wid] = m;
  __syncthreads();
  if (threadIdx.x == 0) part[blockIdx.x] = fmaxf(fmaxf(sm[0], sm[1]), fmaxf(sm[2], sm[3]));
}

__global__ void wmax_final_kernel(const float* __restrict__ part, float* __restrict__ sout) {
  float m = part[threadIdx.x];  // 256 partials
  #pragma unroll
  for (int o = 32; o > 0; o >>= 1) m = fmaxf(m, __shfl_down(m, o));
  __shared__ float sm[4];
  int wid = threadIdx.x >> 6, lane = threadIdx.x & 63;
  if (lane == 0) sm[wid] = m;
  __syncthreads();
  if (threadIdx.x == 0) sout[0] = fmaxf(fmaxf(sm[0], sm[1]), fmaxf(sm[2], sm[3])) / 127.f;
}

// quantize + repack to MFMA-fragment order:
// frag id = (tap*16 + co/16)*8 + ci/32 ; within frag: lane l (0..63), j (0..7)
//   element = W[co16*16 + (l&15)][ci32*32 + (l>>4)*8 + j]
__global__ void quant_kernel(const float* __restrict__ w, const float* __restrict__ sptr,
                             _Float16* __restrict__ wqr, int nw) {
  int d = blockIdx.x * 256 + threadIdx.x;
  if (d >= nw) return;
  int frag = d >> 9;
  int e = d & 511;
  int l = e >> 3, j = e & 7;
  int tap = frag >> 7;
  int rem = frag & 127;
  int cog = rem >> 3, chk = rem & 7;
  int co = cog * 16 + (l & 15);
  int ci = chk * 32 + (l >> 4) * 8 + j;
  float s = sptr[0];
  float q = rintf(w[((size_t)co * 256 + ci) * 9 + tap] / s) * s;  // round-half-even
  wqr[d] = (_Float16)q;
}

// ---------------- pad x (16,3,64,64) fp32 NCHW -> (16,4096,256) f16 NHWC ----
__global__ void pad_kernel(const float* __restrict__ x, _Float16* __restrict__ out) {
  int idx = blockIdx.x * 256 + threadIdx.x;
  int c = idx & 255;
  int pos = idx >> 8;
  int hw = pos & 4095;
  int n = pos >> 12;
  float v = 0.f;
  if (c < 3) v = x[(n * 3 + c) * 4096 + hw];
  out[idx] = (_Float16)v;
}

// ---------------- MFMA conv3x3 + relu + alpha-combine + fused BN partials ---
// grid: (NB*S/R, 4 co-groups of 64). 512 threads = 8 waves (wm=wid>>2 co-half,
// wn=wid&3 pix quarter). K-loop: 8 chunks of 32 ci, taps inner, dbuf LDS.
template <int S, int R>
__global__ __launch_bounds__(512, 2) void conv_mfma_kernel(
    const _Float16* __restrict__ in, const _Float16* __restrict__ wqr,
    const float* __restrict__ alpha, int t,
    const _Float16* __restrict__ h1, const _Float16* __restrict__ h2,
    const _Float16* __restrict__ h3, _Float16* __restrict__ pre,
    const _Float16* __restrict__ zpage,
    float* __restrict__ psum, float* __restrict__ psum2) {
  constexpr int LW = S + 2;
  constexpr int PIX = (R + 2) * LW;
  constexpr int XS = PIX * 4;                    // 16B slots per X buffer
  constexpr int XS_PAD = ((XS + 63) / 64) * 64;  // pad to wave multiple
  constexpr int WS = 36 * 64;                    // 9 taps * 4 cog * 64 slots
  constexpr int PIXB = R * S;                    // pixels per block
  constexpr int G = PIXB / 64;                   // B-frags per wave

  __shared__ half8 xl[2][XS_PAD];
  __shared__ half8 wl[2][WS];
  __shared__ float sred[8][4][2][4];
  __shared__ float sredq[8][4][2][4];

  const int tid = threadIdx.x;
  const int lane = tid & 63;
  const int wid = tid >> 6;
  const int l16 = lane & 15;
  const int kg = lane >> 4;
  const int wm = wid >> 2;   // co 32-sub within block's 64
  const int wn = wid & 3;    // pixel quarter

  constexpr int BPI = S / R;                 // row-blocks per image
  const int n = blockIdx.x / BPI;
  const int rb = blockIdx.x % BPI;
  const int cob = blockIdx.y * 64;           // block co base

  const _Float16* img = in + (size_t)n * S * S * 256;

  floatx4 acc[2][G];
  #pragma unroll
  for (int f = 0; f < 2; ++f)
    #pragma unroll
    for (int g = 0; g < G; ++g)
      acc[f][g] = (floatx4){0.f, 0.f, 0.f, 0.f};

  auto stage = [&](int buf, int c) {
    // X tile: linear LDS dest, swizzled global source, zero page for halo/pad
    const _Float16* cbase = img + c * 32;
    for (int sb = wid * 64; sb < XS_PAD; sb += 512) {
      int slot = sb + lane;
      const void* g = (const void*)zpage;
      if (slot < XS) {
        int pix = slot >> 2;
        int cig = (slot & 3) ^ ((pix >> 1) & 3);
        int hp = pix / LW, wp = pix - hp * LW;
        int h = rb * R + hp - 1, w = wp - 1;
        if ((unsigned)h < (unsigned)S && (unsigned)w < (unsigned)S)
          g = (const void*)(cbase + (size_t)(h * S + w) * 256 + cig * 8);
      }
      gl_lds16(g, (void*)&xl[buf][sb]);
    }
    // W fragments: one coalesced 1KB frag per wave-issue
    for (int fb = wid; fb < 36; fb += 8) {
      int tap = fb >> 2, cogl = fb & 3;
      const _Float16* g = wqr +
          ((((size_t)tap * 16 + blockIdx.y * 4 + cogl) * 8 + c) << 9) + lane * 8;
      gl_lds16((const void*)g, (void*)&wl[buf][fb * 64]);
    }
  };

  auto compute = [&](int buf) {
    #pragma unroll
    for (int dh = -1; dh <= 1; ++dh) {
      #pragma unroll
      for (int dw = -1; dw <= 1; ++dw) {
        const int tap = (dh + 1) * 3 + (dw + 1);
        half8 af[2];
        #pragma unroll
        for (int f = 0; f < 2; ++f)
          af[f] = wl[buf][(tap * 4 + wm * 2 + f) * 64 + lane];
        half8 bf[G];
        #pragma unroll
        for (int g = 0; g < G; ++g) {
          int p = wn * (PIXB / 4) + g * 16 + l16;
          int r = p / S, cc = p - r * S;
          int lp = (r + 1 + dh) * LW + (cc + 1 + dw);
          bf[g] = xl[buf][lp * 4 + (kg ^ ((lp >> 1) & 3))];
        }
        #pragma unroll
        for (int f = 0; f < 2; ++f)
          #pragma unroll
          for (int g = 0; g < G; ++g)
            acc[f][g] = __builtin_amdgcn_mfma_f32_16x16x32_f16(af[f], bf[g], acc[f][g], 0, 0, 0);
      }
    }
  };

  stage(0, 0);
  __syncthreads();
  for (int c = 0; c < 8; ++c) {
    if (c < 7) stage((c + 1) & 1, c + 1);
    compute(c & 1);
    __syncthreads();
  }

  // ---- epilogue: combine + write + per-block BN partials ----
  const float a0 = alpha[t * 5 + 0];
  const float a1 = alpha[t * 5 + 2];
  const float a2 = alpha[t * 5 + 3];
  const float a3 = alpha[t * 5 + 4];
  float ss[2][4], sq[2][4];
  #pragma unroll
  for (int f = 0; f < 2; ++f)
    #pragma unroll
    for (int r = 0; r < 4; ++r) { ss[f][r] = 0.f; sq[f][r] = 0.f; }

  const size_t pix0 = (size_t)n * S * S + (size_t)rb * PIXB;
  #pragma unroll
  for (int f = 0; f < 2; ++f) {
    const int co = cob + wm * 32 + f * 16 + kg * 4;
    #pragma unroll
    for (int g = 0; g < G; ++g) {
      int p = wn * (PIXB / 4) + g * 16 + l16;
      size_t idx = (pix0 + p) * 256 + co;
      half4v v3 = *(const half4v*)(h3 + idx);
      half4v v1 = {}, v2 = {};
      if (h1) v1 = *(const half4v*)(h1 + idx);
      if (h2) v2 = *(const half4v*)(h2 + idx);
      half4v o;
      #pragma unroll
      for (int r = 0; r < 4; ++r) {
        float pv = a0 * fmaxf(acc[f][g][r], 0.f) + a3 * (float)v3[r];
        if (h1) pv += a1 * (float)v1[r];
        if (h2) pv += a2 * (float)v2[r];
        o[r] = (_Float16)pv;
        ss[f][r] += pv;
        sq[f][r] += pv * pv;
      }
      *(half4v*)(pre + idx) = o;  // pre may alias h1: same-thread RaW, safe
    }
  }

  // reduce over the 16 pixel-lanes (same kg group shares channels)
  #pragma unroll
  for (int f = 0; f < 2; ++f)
    #pragma unroll
    for (int r = 0; r < 4; ++r) {
      float a = ss[f][r], b = sq[f][r];
      #pragma unroll
      for (int m = 1; m < 16; m <<= 1) {
        a += __shfl_xor(a, m);
        b += __shfl_xor(b, m);
      }
      if (l16 == 0) { sred[wid][kg][f][r] = a; sredq[wid][kg][f][r] = b; }
    }
  __syncthreads();
  if (tid < 64) {
    int ch = tid;
    int wmm = ch >> 5, ff = (ch >> 4) & 1, kk = (ch >> 2) & 3, rr = ch & 3;
    float a = 0.f, b = 0.f;
    #pragma unroll
    for (int w = 0; w < 4; ++w) {
      a += sred[wmm * 4 + w][kk][ff][rr];
      b += sredq[wmm * 4 + w][kk][ff][rr];
    }
    psum[(size_t)blockIdx.x * 256 + cob + ch] = a;
    psum2[(size_t)blockIdx.x * 256 + cob + ch] = b;
  }
}

// ---------------- BN stats final ---------------------------------------------
__global__ void stats_final_kernel(const float* __restrict__ psum, const float* __restrict__ psum2,
                                   const float* __restrict__ gamma, const float* __restrict__ beta,
                                   int t, float M, int nblk,
                                   float* __restrict__ scale, float* __restrict__ shift) {
  int c = threadIdx.x;
  float s = 0.f, s2 = 0.f;
  for (int b = 0; b < nblk; ++b) {
    s += psum[(size_t)b * 256 + c];
    s2 += psum2[(size_t)b * 256 + c];
  }
  float mean = s / M;
  float var = s2 / M - mean * mean;  // biased, matches jnp.var
  float sc = gamma[t * 256 + c] * rsqrtf(var + 1e-5f);
  scale[c] = sc;
  shift[c] = beta[t * 256 + c] - mean * sc;
}

// ---------------- BN apply (in place, x8 vectorized) ------------------------
__global__ void apply_kernel(_Float16* __restrict__ x, const float* __restrict__ scale,
                             const float* __restrict__ shift, int n8) {
  int i = blockIdx.x * 256 + threadIdx.x;
  if (i >= n8) return;
  half8 v = *(half8*)(x + (size_t)i * 8);
  int c0 = (i * 8) & 255;
  half8 o;
  #pragma unroll
  for (int j = 0; j < 8; ++j) o[j] = (_Float16)((float)v[j] * scale[c0 + j] + shift[c0 + j]);
  *(half8*)(x + (size_t)i * 8) = o;
}

// ---------------- 2x2 max pool (NHWC, x8 channels/thread) -------------------
__global__ void pool_kernel(const _Float16* __restrict__ in, _Float16* __restrict__ out,
                            int So, int total8) {
  int i = blockIdx.x * 256 + threadIdx.x;
  if (i >= total8) return;
  int c0 = (i & 31) * 8;
  int pix = i >> 5;
  int wo = pix % So;
  int t1 = pix / So;
  int ho = t1 % So;
  int n = t1 / So;
  int Si = So * 2;
  size_t b00 = ((size_t)(n * Si * Si) + (2 * ho) * Si + 2 * wo) * 256 + c0;
  half8 v00 = *(const half8*)(in + b00);
  half8 v01 = *(const half8*)(in + b00 + 256);
  half8 v10 = *(const half8*)(in + b00 + (size_t)Si * 256);
  half8 v11 = *(const half8*)(in + b00 + (size_t)Si * 256 + 256);
  half8 o;
  #pragma unroll
  for (int j = 0; j < 8; ++j) {
    float m = fmaxf(fmaxf((float)v00[j], (float)v01[j]), fmaxf((float)v10[j], (float)v11[j]));
    o[j] = (_Float16)m;
  }
  *(half8*)(out + (size_t)pix * 256 + c0) = o;
}

// ---------------- final spatial max (S=4) -> f32 vec ------------------------
__global__ void amax_kernel(const _Float16* __restrict__ x, float* __restrict__ vec) {
  int i = blockIdx.x * blockDim.x + threadIdx.x;  // n*256+c
  if (i >= NB * 256) return;
  int n = i >> 8, c = i & 255;
  float m = -1e30f;
  for (int p = 0; p < 16; ++p)
    m = fmaxf(m, (float)x[((size_t)(n * 16 + p)) * 256 + c]);
  vec[i] = m;
}

// ---------------- linear head ------------------------------------------------
__global__ void linear_kernel(const float* __restrict__ vec, const float* __restrict__ W,
                              const float* __restrict__ b, float* __restrict__ out) {
  int n = blockIdx.x, j = threadIdx.x;
  if (j >= 100) return;
  float s = b[j];
  const float* v = vec + n * 256;
  const float* w = W + j * 256;
  for (int c = 0; c < 256; ++c) s += v[c] * w[c];
  out[n * 100 + j] = s;
}

// ---------------------------------------------------------------------------
static inline void launch_conv(int S, const _Float16* in, const _Float16* wqr,
                               const float* alpha, int t, const _Float16* h1,
                               const _Float16* h2, const _Float16* h3, _Float16* pre,
                               const _Float16* zp, float* psum, float* psum2,
                               hipStream_t stream) {
  dim3 block(512);
  switch (S) {
    case 64: {
      dim3 grid(NB * 16, 4);
      hipLaunchKernelGGL((conv_mfma_kernel<64, 4>), grid, block, 0, stream,
                         in, wqr, alpha, t, h1, h2, h3, pre, zp, psum, psum2);
      break;
    }
    case 32: {
      dim3 grid(NB * 8, 4);
      hipLaunchKernelGGL((conv_mfma_kernel<32, 4>), grid, block, 0, stream,
                         in, wqr, alpha, t, h1, h2, h3, pre, zp, psum, psum2);
      break;
    }
    case 16: {
      dim3 grid(NB * 4, 4);
      hipLaunchKernelGGL((conv_mfma_kernel<16, 4>), grid, block, 0, stream,
                         in, wqr, alpha, t, h1, h2, h3, pre, zp, psum, psum2);
      break;
    }
    case 8: {
      dim3 grid(NB * 1, 4);
      hipLaunchKernelGGL((conv_mfma_kernel<8, 8>), grid, block, 0, stream,
                         in, wqr, alpha, t, h1, h2, h3, pre, zp, psum, psum2);
      break;
    }
  }
}

static inline int conv_nblkx(int S) {
  switch (S) {
    case 64: return NB * 16;
    case 32: return NB * 8;
    case 16: return NB * 4;
    default: return NB * 1;
  }
}

extern "C" void kernel_launch(void* const* d_in, const int* in_sizes, int n_in,
                              void* d_out, int out_size, void* d_ws, size_t ws_size,
                              hipStream_t stream) {
  const float* x        = (const float*)d_in[0];
  const float* conv_w   = (const float*)d_in[1];
  const float* alpha    = (const float*)d_in[2];
  const float* bn_gamma = (const float*)d_in[3];
  const float* bn_beta  = (const float*)d_in[4];
  const float* out_w    = (const float*)d_in[5];
  const float* out_b    = (const float*)d_in[6];
  float* out = (float*)d_out;

  char* ws = (char*)d_ws;
  size_t off = 0;
  auto alloc = [&](size_t bytes) -> void* {
    void* p = (void*)(ws + off);
    off = (off + bytes + 255) & ~(size_t)255;
    return p;
  };
  const size_t FULL_BYTES  = (size_t)NB * 4096 * 256 * 2;  // 32 MiB f16 NHWC
  const size_t SMALL_BYTES = FULL_BYTES / 4;
  _Float16* bufs[4];
  for (int i = 0; i < 3; ++i) bufs[i] = (_Float16*)alloc(FULL_BYTES);
  bufs[3] = (_Float16*)alloc(SMALL_BYTES);
  _Float16* wqr  = (_Float16*)alloc((size_t)9 * 256 * 256 * 2);
  float* wpart = (float*)alloc(256 * 4);
  float* sq    = (float*)alloc(256);
  float* psum  = (float*)alloc(256 * 256 * 4);
  float* psum2 = (float*)alloc(256 * 256 * 4);
  float* scale = (float*)alloc(256 * 4);
  float* shift = (float*)alloc(256 * 4);
  float* vec   = (float*)alloc((size_t)NB * 256 * 4);
  _Float16* zpage = (_Float16*)alloc(256);
  (void)ws_size;  // ~107 MiB

  const int NW = 256 * 256 * 9;

  hipMemsetAsync(zpage, 0, 256, stream);

  // 1) quantize + repack weights to MFMA fragment order
  hipLaunchKernelGGL(wmax_part_kernel, dim3(256), dim3(256), 0, stream, conv_w, wpart, NW);
  hipLaunchKernelGGL(wmax_final_kernel, dim3(1), dim3(256), 0, stream, wpart, sq);
  hipLaunchKernelGGL(quant_kernel, dim3((NW + 255) / 256), dim3(256), 0, stream, conv_w, sq, wqr, NW);

  // 2) pad input -> NHWC f16 slab 0
  hipLaunchKernelGGL(pad_kernel, dim3((NB * 4096 * 256) / 256), dim3(256), 0, stream, x, bufs[0]);

  // 3) 20 iterations
  int i1 = -1, i2 = -1, i3 = 0;
  int S = 64;
  for (int t = 0; t < NIT; ++t) {
    int idst;
    if (i1 >= 0) {
      idst = i1;  // overwrite dying hist[1] in place
    } else {
      idst = -1;
      int limit = (S == 64) ? 3 : 4;
      for (int b = 0; b < limit; ++b)
        if (b != i1 && b != i2 && b != i3) { idst = b; break; }
    }
    const _Float16* h1 = (i1 >= 0) ? bufs[i1] : nullptr;
    const _Float16* h2 = (i2 >= 0) ? bufs[i2] : nullptr;
    const _Float16* h3 = bufs[i3];
    _Float16* pre = bufs[idst];

    launch_conv(S, h3, wqr, alpha, t, h1, h2, h3, pre, zpage, psum, psum2, stream);

    int npix = NB * S * S;
    hipLaunchKernelGGL(stats_final_kernel, dim3(1), dim3(256), 0, stream,
                       psum, psum2, bn_gamma, bn_beta, t, (float)npix, conv_nblkx(S),
                       scale, shift);
    int n8 = npix * 32;
    hipLaunchKernelGGL(apply_kernel, dim3((n8 + 255) / 256), dim3(256), 0, stream,
                       pre, scale, shift, n8);

    i1 = i2; i2 = i3; i3 = idst;

    if (t % 5 == 4) {
      int So = S / 2;
      int total8 = NB * So * So * 32;
      int fr = -1;
      for (int b = 0; b < 4; ++b)
        if (b != i1 && b != i2 && b != i3) { fr = b; break; }
      hipLaunchKernelGGL(pool_kernel, dim3((total8 + 255) / 256), dim3(256), 0, stream,
                         bufs[i1], bufs[fr], So, total8);
      { int old = i1; i1 = fr; fr = old; }
      hipLaunchKernelGGL(pool_kernel, dim3((total8 + 255) / 256), dim3(256), 0, stream,
                         bufs[i2], bufs[fr], So, total8);
      { int old = i2; i2 = fr; fr = old; }
      hipLaunchKernelGGL(pool_kernel, dim3((total8 + 255) / 256), dim3(256), 0, stream,
                         bufs[i3], bufs[fr], So, total8);
      { int old = i3; i3 = fr; fr = old; }
      S = So;
    }
  }

  // 4) final spatial max + linear head
  hipLaunchKernelGGL(amax_kernel, dim3(16), dim3(256), 0, stream, bufs[i3], vec);
  hipLaunchKernelGGL(linear_kernel, dim3(NB), dim3(128), 0, stream, vec, out_w, out_b, out);
}

// Round 5
// 1154.684 us; speedup vs baseline: 16.9159x; 1.4423x over previous
//
#include <hip/hip_runtime.h>
#include <hip/hip_fp16.h>
#include <cstddef>
#include <cstdint>

// QuantizedThriftyNet on MI355X — round 4.
// Round-3 counters: MfmaUtil 24%, VALUBusy 25% -> LDS-read-BW-bound (wave tile
// 32co x 64pix = 21 FLOP/LDS-byte < 32 parity). This round:
//   * conv (S=64/32): 64co x 64pix wave tiles (32 FLOP/B parity), block =
//     64co x 512pix, 8 waves, dbuf X+W LDS ~156 KB, same gl_lds staging
//   * stats_final parallelized (256 blocks x 1 wave)
//   * pool iterations: single fused kernel = BN-apply(new) + pool all 3
//   * S=16/8 keep round-3 kernel (tiny share of time)

#define NB 16
#define NIT 20

typedef _Float16 half8 __attribute__((ext_vector_type(8)));
typedef _Float16 half4v __attribute__((ext_vector_type(4)));
typedef float floatx4 __attribute__((ext_vector_type(4)));

__device__ __forceinline__ void gl_lds16(const void* g, void* l) {
  __builtin_amdgcn_global_load_lds(
      (const __attribute__((address_space(1))) unsigned int*)g,
      (__attribute__((address_space(3))) unsigned int*)l, 16, 0, 0);
}

// ---------------- weight max -> scale ---------------------------------------
__global__ void wmax_part_kernel(const float* __restrict__ w, float* __restrict__ part, int n) {
  float m = 0.f;
  for (int i = blockIdx.x * blockDim.x + threadIdx.x; i < n; i += gridDim.x * blockDim.x)
    m = fmaxf(m, fabsf(w[i]));
  #pragma unroll
  for (int o = 32; o > 0; o >>= 1) m = fmaxf(m, __shfl_down(m, o));
  __shared__ float sm[4];
  int wid = threadIdx.x >> 6, lane = threadIdx.x & 63;
  if (lane == 0) sm[wid] = m;
  __syncthreads();
  if (threadIdx.x == 0) part[blockIdx.x] = fmaxf(fmaxf(sm[0], sm[1]), fmaxf(sm[2], sm[3]));
}

__global__ void wmax_final_kernel(const float* __restrict__ part, float* __restrict__ sout) {
  float m = part[threadIdx.x];
  #pragma unroll
  for (int o = 32; o > 0; o >>= 1) m = fmaxf(m, __shfl_down(m, o));
  __shared__ float sm[4];
  int wid = threadIdx.x >> 6, lane = threadIdx.x & 63;
  if (lane == 0) sm[wid] = m;
  __syncthreads();
  if (threadIdx.x == 0) sout[0] = fmaxf(fmaxf(sm[0], sm[1]), fmaxf(sm[2], sm[3])) / 127.f;
}

// quantize + repack to MFMA-fragment order:
// frag id = (tap*16 + co/16)*8 + ci/32 ; lane l, j: W[co16*16+(l&15)][ci32*32+(l>>4)*8+j]
__global__ void quant_kernel(const float* __restrict__ w, const float* __restrict__ sptr,
                             _Float16* __restrict__ wqr, int nw) {
  int d = blockIdx.x * 256 + threadIdx.x;
  if (d >= nw) return;
  int frag = d >> 9;
  int e = d & 511;
  int l = e >> 3, j = e & 7;
  int tap = frag >> 7;
  int rem = frag & 127;
  int cog = rem >> 3, chk = rem & 7;
  int co = cog * 16 + (l & 15);
  int ci = chk * 32 + (l >> 4) * 8 + j;
  float s = sptr[0];
  float q = rintf(w[((size_t)co * 256 + ci) * 9 + tap] / s) * s;
  wqr[d] = (_Float16)q;
}

// ---------------- pad x fp32 NCHW -> f16 NHWC --------------------------------
__global__ void pad_kernel(const float* __restrict__ x, _Float16* __restrict__ out) {
  int idx = blockIdx.x * 256 + threadIdx.x;
  int c = idx & 255;
  int pos = idx >> 8;
  int hw = pos & 4095;
  int n = pos >> 12;
  float v = 0.f;
  if (c < 3) v = x[(n * 3 + c) * 4096 + hw];
  out[idx] = (_Float16)v;
}

// ---------------- big-tile MFMA conv (S=64/32): 64co x 64pix per wave --------
// grid: (NB * S/R, 4 co-groups of 64); 8 waves; wave wn owns local pixels
// [wn*64, wn*64+64) of the R x S block tile. K = 8 chunks x 9 taps, dbuf LDS.
template <int S, int WR>
__global__ __launch_bounds__(512, 2) void conv_mfma_big(
    const _Float16* __restrict__ in, const _Float16* __restrict__ wqr,
    const float* __restrict__ alpha, int t,
    const _Float16* h1, const _Float16* __restrict__ h2,
    const _Float16* __restrict__ h3, _Float16* pre,
    const _Float16* __restrict__ zpage,
    float* __restrict__ psum, float* __restrict__ psum2) {
  constexpr int R = 8 * WR;                       // rows per block
  constexpr int LW = S + 2;
  constexpr int PIX = (R + 2) * LW;
  constexpr int XS = PIX * 4;
  constexpr int XS_PAD = ((XS + 63) / 64) * 64;
  constexpr int WS = 36 * 64;                     // 9 taps * 4 co-frags * 64 slots

  __shared__ half8 xl[2][XS_PAD];
  __shared__ half8 wl[2][WS];

  const int tid = threadIdx.x;
  const int lane = tid & 63;
  const int wn = tid >> 6;
  const int l16 = lane & 15;
  const int kg = lane >> 4;

  constexpr int BPI = S / R;
  const int n = blockIdx.x / BPI;
  const int rb = blockIdx.x % BPI;
  const int cob = blockIdx.y * 64;

  const _Float16* img = in + (size_t)n * S * S * 256;

  floatx4 acc[4][4];
  #pragma unroll
  for (int f = 0; f < 4; ++f)
    #pragma unroll
    for (int g = 0; g < 4; ++g)
      acc[f][g] = (floatx4){0.f, 0.f, 0.f, 0.f};

  auto stage = [&](int buf, int c) {
    const _Float16* cbase = img + c * 32;
    for (int sb = wn * 64; sb < XS_PAD; sb += 512) {
      int slot = sb + lane;
      const void* g = (const void*)zpage;
      if (slot < XS) {
        int pix = slot >> 2;
        int cig = (slot & 3) ^ ((pix >> 1) & 3);
        int hp = pix / LW, wp = pix - hp * LW;
        int h = rb * R + hp - 1, w = wp - 1;
        if ((unsigned)h < (unsigned)S && (unsigned)w < (unsigned)S)
          g = (const void*)(cbase + (size_t)(h * S + w) * 256 + cig * 8);
      }
      gl_lds16(g, (void*)&xl[buf][sb]);
    }
    for (int fb = wn; fb < 36; fb += 8) {
      int tap = fb >> 2, cf = fb & 3;
      const _Float16* g = wqr +
          ((((size_t)tap * 16 + blockIdx.y * 4 + cf) * 8 + c) << 9) + lane * 8;
      gl_lds16((const void*)g, (void*)&wl[buf][fb * 64]);
    }
  };

  auto compute = [&](int buf) {
    #pragma unroll
    for (int dh = -1; dh <= 1; ++dh) {
      #pragma unroll
      for (int dw = -1; dw <= 1; ++dw) {
        const int tap = (dh + 1) * 3 + (dw + 1);
        half8 af[4];
        #pragma unroll
        for (int f = 0; f < 4; ++f)
          af[f] = wl[buf][(tap * 4 + f) * 64 + lane];
        half8 bf[4];
        #pragma unroll
        for (int g = 0; g < 4; ++g) {
          int lp = wn * 64 + g * 16 + l16;
          int r = lp / S, cc = lp - r * S;
          int xp = (r + 1 + dh) * LW + (cc + 1 + dw);
          bf[g] = xl[buf][xp * 4 + (kg ^ ((xp >> 1) & 3))];
        }
        #pragma unroll
        for (int f = 0; f < 4; ++f)
          #pragma unroll
          for (int g = 0; g < 4; ++g)
            acc[f][g] = __builtin_amdgcn_mfma_f32_16x16x32_f16(af[f], bf[g], acc[f][g], 0, 0, 0);
      }
    }
  };

  stage(0, 0);
  __syncthreads();
  for (int c = 0; c < 8; ++c) {
    if (c < 7) stage((c + 1) & 1, c + 1);
    compute(c & 1);
    __syncthreads();
  }

  // ---- epilogue: combine + write + fused BN partials ----
  const float a0 = alpha[t * 5 + 0];
  const float a1 = alpha[t * 5 + 2];
  const float a2 = alpha[t * 5 + 3];
  const float a3 = alpha[t * 5 + 4];
  float ss[4][4], s2[4][4];
  #pragma unroll
  for (int f = 0; f < 4; ++f)
    #pragma unroll
    for (int r = 0; r < 4; ++r) { ss[f][r] = 0.f; s2[f][r] = 0.f; }

  const size_t pixbase = (size_t)n * S * S + (size_t)rb * R * S;
  #pragma unroll
  for (int f = 0; f < 4; ++f) {
    const int co = cob + f * 16 + kg * 4;
    #pragma unroll
    for (int g = 0; g < 4; ++g) {
      int lp = wn * 64 + g * 16 + l16;
      size_t idx = (pixbase + lp) * 256 + co;
      half4v v3 = *(const half4v*)(h3 + idx);
      half4v v1 = {}, v2 = {};
      if (h1) v1 = *(const half4v*)(h1 + idx);
      if (h2) v2 = *(const half4v*)(h2 + idx);
      half4v o;
      #pragma unroll
      for (int r = 0; r < 4; ++r) {
        float pv = a0 * fmaxf(acc[f][g][r], 0.f) + a3 * (float)v3[r];
        if (h1) pv += a1 * (float)v1[r];
        if (h2) pv += a2 * (float)v2[r];
        o[r] = (_Float16)pv;
        ss[f][r] += pv;
        s2[f][r] += pv * pv;
      }
      *(half4v*)(pre + idx) = o;  // pre may alias h1: same-thread RaW, safe
    }
  }

  // reduce over the 16 pixel-lanes; partials into dead wl[0] space
  float* sred = (float*)(&wl[0][0]);  // 512 ss + 512 sq floats
  #pragma unroll
  for (int f = 0; f < 4; ++f)
    #pragma unroll
    for (int r = 0; r < 4; ++r) {
      float a = ss[f][r], b = s2[f][r];
      #pragma unroll
      for (int m = 1; m < 16; m <<= 1) {
        a += __shfl_xor(a, m);
        b += __shfl_xor(b, m);
      }
      if (l16 == 0) {
        sred[wn * 64 + f * 16 + kg * 4 + r] = a;
        sred[512 + wn * 64 + f * 16 + kg * 4 + r] = b;
      }
    }
  __syncthreads();
  if (tid < 64) {
    float a = 0.f, b = 0.f;
    #pragma unroll
    for (int w = 0; w < 8; ++w) {
      a += sred[w * 64 + tid];
      b += sred[512 + w * 64 + tid];
    }
    psum[(size_t)blockIdx.x * 256 + cob + tid] = a;
    psum2[(size_t)blockIdx.x * 256 + cob + tid] = b;
  }
}

// ---------------- round-3 kernel kept for S=16/8 -----------------------------
template <int S, int R>
__global__ __launch_bounds__(512, 2) void conv_mfma_sm(
    const _Float16* __restrict__ in, const _Float16* __restrict__ wqr,
    const float* __restrict__ alpha, int t,
    const _Float16* h1, const _Float16* __restrict__ h2,
    const _Float16* __restrict__ h3, _Float16* pre,
    const _Float16* __restrict__ zpage,
    float* __restrict__ psum, float* __restrict__ psum2) {
  constexpr int LW = S + 2;
  constexpr int PIX = (R + 2) * LW;
  constexpr int XS = PIX * 4;
  constexpr int XS_PAD = ((XS + 63) / 64) * 64;
  constexpr int WS = 36 * 64;
  constexpr int PIXB = R * S;
  constexpr int G = PIXB / 64;

  __shared__ half8 xl[2][XS_PAD];
  __shared__ half8 wl[2][WS];
  __shared__ float sred[8][4][2][4];
  __shared__ float sredq[8][4][2][4];

  const int tid = threadIdx.x;
  const int lane = tid & 63;
  const int wid = tid >> 6;
  const int l16 = lane & 15;
  const int kg = lane >> 4;
  const int wm = wid >> 2;
  const int wn = wid & 3;

  constexpr int BPI = S / R;
  const int n = blockIdx.x / BPI;
  const int rb = blockIdx.x % BPI;
  const int cob = blockIdx.y * 64;

  const _Float16* img = in + (size_t)n * S * S * 256;

  floatx4 acc[2][G];
  #pragma unroll
  for (int f = 0; f < 2; ++f)
    #pragma unroll
    for (int g = 0; g < G; ++g)
      acc[f][g] = (floatx4){0.f, 0.f, 0.f, 0.f};

  auto stage = [&](int buf, int c) {
    const _Float16* cbase = img + c * 32;
    for (int sb = wid * 64; sb < XS_PAD; sb += 512) {
      int slot = sb + lane;
      const void* g = (const void*)zpage;
      if (slot < XS) {
        int pix = slot >> 2;
        int cig = (slot & 3) ^ ((pix >> 1) & 3);
        int hp = pix / LW, wp = pix - hp * LW;
        int h = rb * R + hp - 1, w = wp - 1;
        if ((unsigned)h < (unsigned)S && (unsigned)w < (unsigned)S)
          g = (const void*)(cbase + (size_t)(h * S + w) * 256 + cig * 8);
      }
      gl_lds16(g, (void*)&xl[buf][sb]);
    }
    for (int fb = wid; fb < 36; fb += 8) {
      int tap = fb >> 2, cogl = fb & 3;
      const _Float16* g = wqr +
          ((((size_t)tap * 16 + blockIdx.y * 4 + cogl) * 8 + c) << 9) + lane * 8;
      gl_lds16((const void*)g, (void*)&wl[buf][fb * 64]);
    }
  };

  auto compute = [&](int buf) {
    #pragma unroll
    for (int dh = -1; dh <= 1; ++dh) {
      #pragma unroll
      for (int dw = -1; dw <= 1; ++dw) {
        const int tap = (dh + 1) * 3 + (dw + 1);
        half8 af[2];
        #pragma unroll
        for (int f = 0; f < 2; ++f)
          af[f] = wl[buf][(tap * 4 + wm * 2 + f) * 64 + lane];
        half8 bf[G];
        #pragma unroll
        for (int g = 0; g < G; ++g) {
          int p = wn * (PIXB / 4) + g * 16 + l16;
          int r = p / S, cc = p - r * S;
          int lp = (r + 1 + dh) * LW + (cc + 1 + dw);
          bf[g] = xl[buf][lp * 4 + (kg ^ ((lp >> 1) & 3))];
        }
        #pragma unroll
        for (int f = 0; f < 2; ++f)
          #pragma unroll
          for (int g = 0; g < G; ++g)
            acc[f][g] = __builtin_amdgcn_mfma_f32_16x16x32_f16(af[f], bf[g], acc[f][g], 0, 0, 0);
      }
    }
  };

  stage(0, 0);
  __syncthreads();
  for (int c = 0; c < 8; ++c) {
    if (c < 7) stage((c + 1) & 1, c + 1);
    compute(c & 1);
    __syncthreads();
  }

  const float a0 = alpha[t * 5 + 0];
  const float a1 = alpha[t * 5 + 2];
  const float a2 = alpha[t * 5 + 3];
  const float a3 = alpha[t * 5 + 4];
  float ss[2][4], sq[2][4];
  #pragma unroll
  for (int f = 0; f < 2; ++f)
    #pragma unroll
    for (int r = 0; r < 4; ++r) { ss[f][r] = 0.f; sq[f][r] = 0.f; }

  const size_t pix0 = (size_t)n * S * S + (size_t)rb * PIXB;
  #pragma unroll
  for (int f = 0; f < 2; ++f) {
    const int co = cob + wm * 32 + f * 16 + kg * 4;
    #pragma unroll
    for (int g = 0; g < G; ++g) {
      int p = wn * (PIXB / 4) + g * 16 + l16;
      size_t idx = (pix0 + p) * 256 + co;
      half4v v3 = *(const half4v*)(h3 + idx);
      half4v v1 = {}, v2 = {};
      if (h1) v1 = *(const half4v*)(h1 + idx);
      if (h2) v2 = *(const half4v*)(h2 + idx);
      half4v o;
      #pragma unroll
      for (int r = 0; r < 4; ++r) {
        float pv = a0 * fmaxf(acc[f][g][r], 0.f) + a3 * (float)v3[r];
        if (h1) pv += a1 * (float)v1[r];
        if (h2) pv += a2 * (float)v2[r];
        o[r] = (_Float16)pv;
        ss[f][r] += pv;
        sq[f][r] += pv * pv;
      }
      *(half4v*)(pre + idx) = o;
    }
  }

  #pragma unroll
  for (int f = 0; f < 2; ++f)
    #pragma unroll
    for (int r = 0; r < 4; ++r) {
      float a = ss[f][r], b = sq[f][r];
      #pragma unroll
      for (int m = 1; m < 16; m <<= 1) {
        a += __shfl_xor(a, m);
        b += __shfl_xor(b, m);
      }
      if (l16 == 0) { sred[wid][kg][f][r] = a; sredq[wid][kg][f][r] = b; }
    }
  __syncthreads();
  if (tid < 64) {
    int ch = tid;
    int wmm = ch >> 5, ff = (ch >> 4) & 1, kk = (ch >> 2) & 3, rr = ch & 3;
    float a = 0.f, b = 0.f;
    #pragma unroll
    for (int w = 0; w < 4; ++w) {
      a += sred[wmm * 4 + w][kk][ff][rr];
      b += sredq[wmm * 4 + w][kk][ff][rr];
    }
    psum[(size_t)blockIdx.x * 256 + cob + ch] = a;
    psum2[(size_t)blockIdx.x * 256 + cob + ch] = b;
  }
}

// ---------------- BN stats final (256 blocks x 1 wave) ------------------------
__global__ void stats_final_kernel(const float* __restrict__ psum, const float* __restrict__ psum2,
                                   const float* __restrict__ gamma, const float* __restrict__ beta,
                                   int t, float M, int nblk,
                                   float* __restrict__ scale, float* __restrict__ shift) {
  int c = blockIdx.x;
  float s = 0.f, s2 = 0.f;
  for (int b = threadIdx.x; b < nblk; b += 64) {
    s += psum[(size_t)b * 256 + c];
    s2 += psum2[(size_t)b * 256 + c];
  }
  #pragma unroll
  for (int o = 32; o > 0; o >>= 1) {
    s += __shfl_down(s, o);
    s2 += __shfl_down(s2, o);
  }
  if (threadIdx.x == 0) {
    float mean = s / M;
    float var = s2 / M - mean * mean;  // biased, matches jnp.var
    float sc = gamma[t * 256 + c] * rsqrtf(var + 1e-5f);
    scale[c] = sc;
    shift[c] = beta[t * 256 + c] - mean * sc;
  }
}

// ---------------- BN apply (in place, non-pool iters) -------------------------
__global__ void apply_kernel(_Float16* __restrict__ x, const float* __restrict__ scale,
                             const float* __restrict__ shift, int n8) {
  int i = blockIdx.x * 256 + threadIdx.x;
  if (i >= n8) return;
  half8 v = *(half8*)(x + (size_t)i * 8);
  int c0 = (i * 8) & 255;
  half8 o;
  #pragma unroll
  for (int j = 0; j < 8; ++j) o[j] = (_Float16)((float)v[j] * scale[c0 + j] + shift[c0 + j]);
  *(half8*)(x + (size_t)i * 8) = o;
}

// ---------------- fused pool (3 tensors) + BN-apply on tensor z==2 ------------
__global__ void pool3_kernel(const _Float16* __restrict__ s0, const _Float16* __restrict__ s1,
                             const _Float16* __restrict__ s2,
                             _Float16* __restrict__ d0, _Float16* __restrict__ d1,
                             _Float16* __restrict__ d2,
                             const float* __restrict__ scale, const float* __restrict__ shift,
                             int So, int total8) {
  int i = blockIdx.x * 256 + threadIdx.x;
  if (i >= total8) return;
  int z = blockIdx.y;
  const _Float16* in = (z == 0) ? s0 : (z == 1) ? s1 : s2;
  _Float16* out = (z == 0) ? d0 : (z == 1) ? d1 : d2;
  int c0 = (i & 31) * 8;
  int pix = i >> 5;
  int wo = pix % So;
  int t1 = pix / So;
  int ho = t1 % So;
  int n = t1 / So;
  int Si = So * 2;
  size_t b00 = ((size_t)(n * Si * Si) + (2 * ho) * Si + 2 * wo) * 256 + c0;
  half8 v00 = *(const half8*)(in + b00);
  half8 v01 = *(const half8*)(in + b00 + 256);
  half8 v10 = *(const half8*)(in + b00 + (size_t)Si * 256);
  half8 v11 = *(const half8*)(in + b00 + (size_t)Si * 256 + 256);
  half8 o;
  if (z == 2) {
    #pragma unroll
    for (int j = 0; j < 8; ++j) {
      float sc = scale[c0 + j], sh = shift[c0 + j];
      float a = (float)v00[j] * sc + sh;
      float b = (float)v01[j] * sc + sh;
      float c = (float)v10[j] * sc + sh;
      float d = (float)v11[j] * sc + sh;
      o[j] = (_Float16)fmaxf(fmaxf(a, b), fmaxf(c, d));
    }
  } else {
    #pragma unroll
    for (int j = 0; j < 8; ++j) {
      float m = fmaxf(fmaxf((float)v00[j], (float)v01[j]),
                      fmaxf((float)v10[j], (float)v11[j]));
      o[j] = (_Float16)m;
    }
  }
  *(half8*)(out + (size_t)pix * 256 + c0) = o;
}

// ---------------- final spatial max (S=4) -> f32 vec --------------------------
__global__ void amax_kernel(const _Float16* __restrict__ x, float* __restrict__ vec) {
  int i = blockIdx.x * blockDim.x + threadIdx.x;
  if (i >= NB * 256) return;
  int n = i >> 8, c = i & 255;
  float m = -1e30f;
  for (int p = 0; p < 16; ++p)
    m = fmaxf(m, (float)x[((size_t)(n * 16 + p)) * 256 + c]);
  vec[i] = m;
}

// ---------------- linear head --------------------------------------------------
__global__ void linear_kernel(const float* __restrict__ vec, const float* __restrict__ W,
                              const float* __restrict__ b, float* __restrict__ out) {
  int n = blockIdx.x, j = threadIdx.x;
  if (j >= 100) return;
  float s = b[j];
  const float* v = vec + n * 256;
  const float* w = W + j * 256;
  for (int c = 0; c < 256; ++c) s += v[c] * w[c];
  out[n * 100 + j] = s;
}

// -------------------------------------------------------------------------------
extern "C" void kernel_launch(void* const* d_in, const int* in_sizes, int n_in,
                              void* d_out, int out_size, void* d_ws, size_t ws_size,
                              hipStream_t stream) {
  const float* x        = (const float*)d_in[0];
  const float* conv_w   = (const float*)d_in[1];
  const float* alpha    = (const float*)d_in[2];
  const float* bn_gamma = (const float*)d_in[3];
  const float* bn_beta  = (const float*)d_in[4];
  const float* out_w    = (const float*)d_in[5];
  const float* out_b    = (const float*)d_in[6];
  float* out = (float*)d_out;

  char* ws = (char*)d_ws;
  size_t off = 0;
  auto alloc = [&](size_t bytes) -> void* {
    void* p = (void*)(ws + off);
    off = (off + bytes + 255) & ~(size_t)255;
    return p;
  };
  const size_t SLAB = (size_t)NB * 4096 * 256 * 2;  // 32 MiB
  char* slab[4];
  size_t slabsz[4];
  for (int i = 0; i < 3; ++i) { slab[i] = (char*)alloc(SLAB); slabsz[i] = SLAB; }
  slab[3] = (char*)alloc(3 * (SLAB / 4)); slabsz[3] = 3 * (SLAB / 4);  // 24 MiB
  _Float16* wqr  = (_Float16*)alloc((size_t)9 * 256 * 256 * 2);
  float* wpart = (float*)alloc(256 * 4);
  float* sq    = (float*)alloc(256);
  float* psum  = (float*)alloc(256 * 256 * 4);
  float* psum2 = (float*)alloc(256 * 256 * 4);
  float* scale = (float*)alloc(256 * 4);
  float* shift = (float*)alloc(256 * 4);
  float* vec   = (float*)alloc((size_t)NB * 256 * 4);
  _Float16* zpage = (_Float16*)alloc(256);
  (void)ws_size;  // ~123 MiB

  const int NW = 256 * 256 * 9;

  hipMemsetAsync(zpage, 0, 256, stream);

  hipLaunchKernelGGL(wmax_part_kernel, dim3(256), dim3(256), 0, stream, conv_w, wpart, NW);
  hipLaunchKernelGGL(wmax_final_kernel, dim3(1), dim3(256), 0, stream, wpart, sq);
  hipLaunchKernelGGL(quant_kernel, dim3((NW + 255) / 256), dim3(256), 0, stream, conv_w, sq, wqr, NW);

  hipLaunchKernelGGL(pad_kernel, dim3((NB * 4096 * 256) / 256), dim3(256), 0, stream,
                     x, (_Float16*)slab[0]);

  auto contains = [&](int k, char* p) -> bool {
    return p && p >= slab[k] && p < slab[k] + slabsz[k];
  };

  char *p1 = nullptr, *p2 = nullptr, *p3 = slab[0];
  int S = 64;
  for (int t = 0; t < NIT; ++t) {
    char* dst;
    if (p1) {
      dst = p1;  // overwrite dying hist[1] in place
    } else {
      dst = nullptr;
      for (int k = 0; k < 3; ++k)
        if (!contains(k, p2) && !contains(k, p3)) { dst = slab[k]; break; }
    }
    const _Float16* h1 = (const _Float16*)p1;
    const _Float16* h2 = (const _Float16*)p2;
    const _Float16* h3 = (const _Float16*)p3;
    _Float16* pre = (_Float16*)dst;

    int nblk;
    dim3 block(512);
    switch (S) {
      case 64: {
        dim3 grid(NB * 8, 4);  nblk = NB * 8;
        hipLaunchKernelGGL((conv_mfma_big<64, 1>), grid, block, 0, stream,
                           h3, wqr, alpha, t, h1, h2, h3, pre, zpage, psum, psum2);
        break;
      }
      case 32: {
        dim3 grid(NB * 2, 4);  nblk = NB * 2;
        hipLaunchKernelGGL((conv_mfma_big<32, 2>), grid, block, 0, stream,
                           h3, wqr, alpha, t, h1, h2, h3, pre, zpage, psum, psum2);
        break;
      }
      case 16: {
        dim3 grid(NB * 4, 4);  nblk = NB * 4;
        hipLaunchKernelGGL((conv_mfma_sm<16, 4>), grid, block, 0, stream,
                           h3, wqr, alpha, t, h1, h2, h3, pre, zpage, psum, psum2);
        break;
      }
      default: {
        dim3 grid(NB * 1, 4);  nblk = NB * 1;
        hipLaunchKernelGGL((conv_mfma_sm<8, 8>), grid, block, 0, stream,
                           h3, wqr, alpha, t, h1, h2, h3, pre, zpage, psum, psum2);
        break;
      }
    }

    int npix = NB * S * S;
    hipLaunchKernelGGL(stats_final_kernel, dim3(256), dim3(64), 0, stream,
                       psum, psum2, bn_gamma, bn_beta, t, (float)npix, nblk, scale, shift);

    if (t % 5 != 4) {
      int n8 = npix * 32;
      hipLaunchKernelGGL(apply_kernel, dim3((n8 + 255) / 256), dim3(256), 0, stream,
                         pre, scale, shift, n8);
      p1 = p2; p2 = p3; p3 = dst;
    } else {
      // post-shift live set: q1 (no apply), q2 (no apply), q3 = new (apply)
      char* q1 = p2;
      char* q2 = p3;
      char* q3 = dst;
      int So = S / 2;
      size_t qbytes = (size_t)NB * So * So * 256 * 2;
      char* fs = nullptr;
      for (int k = 0; k < 4; ++k)
        if (!contains(k, q1) && !contains(k, q2) && !contains(k, q3)) { fs = slab[k]; break; }
      int total8 = NB * So * So * 32;
      dim3 pg((total8 + 255) / 256, 3);
      hipLaunchKernelGGL(pool3_kernel, pg, dim3(256), 0, stream,
                         (const _Float16*)q1, (const _Float16*)q2, (const _Float16*)q3,
                         (_Float16*)fs, (_Float16*)(fs + qbytes), (_Float16*)(fs + 2 * qbytes),
                         scale, shift, So, total8);
      p1 = fs; p2 = fs + qbytes; p3 = fs + 2 * qbytes;
      S = So;
    }
  }

  hipLaunchKernelGGL(amax_kernel, dim3(16), dim3(256), 0, stream, (const _Float16*)p3, vec);
  hipLaunchKernelGGL(linear_kernel, dim3(NB), dim3(128), 0, stream, vec, out_w, out_b, out);
}